// Round 11
// baseline (973.832 us; speedup 1.0000x reference)
//
#include <hip/hip_runtime.h>
#include <hip/hip_bf16.h>

#define N_NODES_C 100000
#define N_EDGES_C 1600000
#define HID_C 128
#define NCLS_C 16
#define NGRAPH_C 512
#define ELL_CAP 64

#define NBKT 256
#define NRANGE 391  // ceil(100000/256); 256*391 = 100096 >= N
#define RCAP 1024   // per-replica bucket capacity (mean 781, +8.7 sigma)
#define NREP 8

#define GEMM_BLOCKS ((N_NODES_C + 127) / 128)  // 782
#define B1_BLOCKS 1024
#define GS_BLOCKS ((N_NODES_C + 255) / 256)  // 391
#define FRONT_BLOCKS (B1_BLOCKS + GEMM_BLOCKS + GS_BLOCKS)

// ---------------- GEMM body (pure U = A @ W, no scale), shared ----------------
__device__ __forceinline__ void gemm_body(
    const float* __restrict__ A, const float* __restrict__ W,
    float* __restrict__ U, int m0, float (*sA)[132], float (*sB)[132]) {
  int t = threadIdx.x;
  int tx = t & 15, ty = t >> 4;

  float acc[8][8];
#pragma unroll
  for (int i = 0; i < 8; ++i)
#pragma unroll
    for (int j = 0; j < 8; ++j) acc[i][j] = 0.f;

  int a_c4 = (t & 7) * 4;
  int a_r = t >> 3;
  int w_n4 = (t & 31) * 4;
  int w_k = t >> 5;

  for (int k0 = 0; k0 < HID_C; k0 += 32) {
#pragma unroll
    for (int rr = 0; rr < 4; ++rr) {
      int r = rr * 32 + a_r;
      int row = m0 + r;
      float4 v = make_float4(0.f, 0.f, 0.f, 0.f);
      if (row < N_NODES_C) v = *(const float4*)&A[(size_t)row * HID_C + k0 + a_c4];
      sA[a_c4 + 0][r] = v.x;
      sA[a_c4 + 1][r] = v.y;
      sA[a_c4 + 2][r] = v.z;
      sA[a_c4 + 3][r] = v.w;
    }
#pragma unroll
    for (int i = 0; i < 4; ++i) {
      int kc = i * 8 + w_k;
      float4 v = *(const float4*)&W[(size_t)(k0 + kc) * HID_C + w_n4];
      *(float4*)&sB[kc][w_n4] = v;
    }
    __syncthreads();

#pragma unroll 4
    for (int kk = 0; kk < 32; ++kk) {
      float4 a0 = *(const float4*)&sA[kk][ty * 8];
      float4 a1 = *(const float4*)&sA[kk][ty * 8 + 4];
      float4 bb0 = *(const float4*)&sB[kk][tx * 8];
      float4 bb1 = *(const float4*)&sB[kk][tx * 8 + 4];
      float a[8] = {a0.x, a0.y, a0.z, a0.w, a1.x, a1.y, a1.z, a1.w};
      float b[8] = {bb0.x, bb0.y, bb0.z, bb0.w, bb1.x, bb1.y, bb1.z, bb1.w};
#pragma unroll
      for (int i = 0; i < 8; ++i)
#pragma unroll
        for (int j = 0; j < 8; ++j) acc[i][j] = fmaf(a[i], b[j], acc[i][j]);
    }
    __syncthreads();
  }

#pragma unroll
  for (int i = 0; i < 8; ++i) {
    int row = m0 + ty * 8 + i;
    if (row < N_NODES_C) {
      float4 v0 = {acc[i][0], acc[i][1], acc[i][2], acc[i][3]};
      float4 v1 = {acc[i][4], acc[i][5], acc[i][6], acc[i][7]};
      float4* p = (float4*)&U[(size_t)row * HID_C + tx * 8];
      p[0] = v0;
      p[1] = v1;
    }
  }
}

// ---------------- FRONT: B1 bucket-scatter || gemm1 || gstart ----------------
// B1: append (d,s) into dst-range buckets and s into src-range buckets.
// Contiguous append regions => line-dense writes (vs scattered ELL stores).
// gemm1 (U1 = x@W1) is independent (rowscale deferred to agg).
__global__ __launch_bounds__(256) void k_front(
    const float* __restrict__ x, const float* __restrict__ W1,
    float* __restrict__ U1, const int* __restrict__ src,
    const int* __restrict__ dst, int* bcur, int2* __restrict__ dstbkt,
    int* __restrict__ srcbkt, const int* __restrict__ gid,
    int* __restrict__ gstart) {
  __shared__ float sA[32][132];
  __shared__ float sB[32][132];
  int bid = blockIdx.x;
  if (bid < B1_BLOCKS) {
    int r = bid & (NREP - 1);
    int i = bid * 256 + threadIdx.x;
    int stride = B1_BLOCKS * 256;
    for (; i < N_EDGES_C; i += stride) {
      int s = src[i];
      int d = dst[i];
      int bd = d / NRANGE;
      int pd = atomicAdd(&bcur[bd * NREP + r], 1);
      if (pd < RCAP) dstbkt[((bd * NREP + r) << 10) + pd] = make_int2(d, s);
      int bs = s / NRANGE;
      int ps = atomicAdd(&bcur[NBKT * NREP + bs * NREP + r], 1);
      if (ps < RCAP) srcbkt[((bs * NREP + r) << 10) + ps] = s;
    }
  } else if (bid < B1_BLOCKS + GEMM_BLOCKS) {
    gemm_body(x, W1, U1, (bid - B1_BLOCKS) * 128, sA, sB);
  } else {
    int n = (bid - B1_BLOCKS - GEMM_BLOCKS) * 256 + threadIdx.x;
    if (n >= N_NODES_C) return;
    int g = gid[n];
    int gp = (n == 0) ? -1 : gid[n - 1];
    for (int k = gp + 1; k <= g; ++k) gstart[k] = n;
    if (n == N_NODES_C - 1) {
      for (int k = g + 1; k <= NGRAPH_C; ++k) gstart[k] = N_NODES_C;
    }
  }
}

// ---------------- BUILD: blocks 0..255 = ELL + cnt_in; 256..511 = cnt_out ----
// Block b owns node range [b*391, +391): LDS cursors (no global atomics),
// private 100KB ELL window => one-XCD dense writeback.
__global__ __launch_bounds__(256) void k_build(
    const int* __restrict__ bcur, const int2* __restrict__ dstbkt,
    const int* __restrict__ srcbkt, int* __restrict__ ell,
    int* __restrict__ cnt_in, int* __restrict__ cnt_out) {
  __shared__ int lcur[NRANGE];
  int tid = threadIdx.x;
  int bid = blockIdx.x;
  for (int t = tid; t < NRANGE; t += 256) lcur[t] = 0;
  __syncthreads();
  if (bid < NBKT) {
    int b = bid;
    int lo = b * NRANGE;
    int nr = N_NODES_C - lo;
    if (nr > NRANGE) nr = NRANGE;
#pragma unroll 1
    for (int r = 0; r < NREP; ++r) {
      int len = bcur[b * NREP + r];
      if (len > RCAP) len = RCAP;
      const int2* slice = dstbkt + ((size_t)(b * NREP + r) << 10);
      for (int j = tid; j < len; j += 256) {
        int2 e = slice[j];
        int p = atomicAdd(&lcur[e.x - lo], 1);
        if (p < ELL_CAP) ell[((size_t)e.x << 6) + p] = e.y;
      }
    }
    __syncthreads();
    for (int t = tid; t < nr; t += 256) cnt_in[lo + t] = lcur[t];
  } else {
    int b = bid - NBKT;
    int lo = b * NRANGE;
    int nr = N_NODES_C - lo;
    if (nr > NRANGE) nr = NRANGE;
#pragma unroll 1
    for (int r = 0; r < NREP; ++r) {
      int len = bcur[NBKT * NREP + b * NREP + r];
      if (len > RCAP) len = RCAP;
      const int* slice = srcbkt + ((size_t)(b * NREP + r) << 10);
      for (int j = tid; j < len; j += 256) {
        atomicAdd(&lcur[slice[j] - lo], 1);
      }
    }
    __syncthreads();
    for (int t = tid; t < nr; t += 256) cnt_out[lo + t] = lcur[t];
  }
}

// ---------------- plain GEMM kernel (layers 2..4): U = H @ W ----------------
__global__ __launch_bounds__(256) void k_gemm(
    const float* __restrict__ A, const float* __restrict__ W,
    float* __restrict__ U) {
  __shared__ float sA[32][132];
  __shared__ float sB[32][132];
  gemm_body(A, W, U, blockIdx.x * 128, sA, sB);
}

// ---------------- aggregation (ELL, deferred norms) ----------------
// H[n] = relu( nd[n] * sum_e ns[ell[n][e]] * U[ell[n][e]] + b )
__global__ __launch_bounds__(256) void k_agg(
    const float* __restrict__ U, const int* __restrict__ cnt_in,
    const int* __restrict__ cnt_out, const int* __restrict__ ell,
    const float* __restrict__ bias, float* __restrict__ H) {
  int wid = threadIdx.x >> 6, lane = threadIdx.x & 63;
  int half = lane >> 5, li = lane & 31;
  int n = blockIdx.x * 4 + wid;
  if (n >= N_NODES_C) return;
  const int* lst = ell + ((size_t)n << 6);
  int degfull = cnt_in[n];
  int deg = degfull > ELL_CAP ? ELL_CAP : degfull;
  const float4* U4 = (const float4*)U;
  float4 acc = make_float4(0.f, 0.f, 0.f, 0.f);
  int e = 0;
  for (; e + 8 <= deg; e += 8) {
    int i0 = lst[e + 0 + half], i1 = lst[e + 2 + half];
    int i2 = lst[e + 4 + half], i3 = lst[e + 6 + half];
    float s0 = 1.f / sqrtf((float)cnt_out[i0]);
    float s1 = 1.f / sqrtf((float)cnt_out[i1]);
    float s2 = 1.f / sqrtf((float)cnt_out[i2]);
    float s3 = 1.f / sqrtf((float)cnt_out[i3]);
    float4 v0 = U4[(size_t)i0 * 32 + li];
    float4 v1 = U4[(size_t)i1 * 32 + li];
    float4 v2 = U4[(size_t)i2 * 32 + li];
    float4 v3 = U4[(size_t)i3 * 32 + li];
    acc.x = fmaf(v0.x, s0, fmaf(v1.x, s1, fmaf(v2.x, s2, fmaf(v3.x, s3, acc.x))));
    acc.y = fmaf(v0.y, s0, fmaf(v1.y, s1, fmaf(v2.y, s2, fmaf(v3.y, s3, acc.y))));
    acc.z = fmaf(v0.z, s0, fmaf(v1.z, s1, fmaf(v2.z, s2, fmaf(v3.z, s3, acc.z))));
    acc.w = fmaf(v0.w, s0, fmaf(v1.w, s1, fmaf(v2.w, s2, fmaf(v3.w, s3, acc.w))));
  }
  for (; e + 2 <= deg; e += 2) {
    int i = lst[e + half];
    float s = 1.f / sqrtf((float)cnt_out[i]);
    float4 v = U4[(size_t)i * 32 + li];
    acc.x = fmaf(v.x, s, acc.x);
    acc.y = fmaf(v.y, s, acc.y);
    acc.z = fmaf(v.z, s, acc.z);
    acc.w = fmaf(v.w, s, acc.w);
  }
  if (e < deg) {  // odd tail: low half only
    int i = lst[e];
    float s = 1.f / sqrtf((float)cnt_out[i]);
    float4 v = U4[(size_t)i * 32 + li];
    if (half == 0) {
      acc.x = fmaf(v.x, s, acc.x);
      acc.y = fmaf(v.y, s, acc.y);
      acc.z = fmaf(v.z, s, acc.z);
      acc.w = fmaf(v.w, s, acc.w);
    }
  }
  acc.x += __shfl_xor(acc.x, 32);
  acc.y += __shfl_xor(acc.y, 32);
  acc.z += __shfl_xor(acc.z, 32);
  acc.w += __shfl_xor(acc.w, 32);
  if (half == 0) {
    float nd = 1.f / sqrtf(fmaxf((float)degfull, 1.f));
    float4 bb = ((const float4*)bias)[li];
    float4 r;
    r.x = fmaxf(fmaf(acc.x, nd, bb.x), 0.f);
    r.y = fmaxf(fmaf(acc.y, nd, bb.y), 0.f);
    r.z = fmaxf(fmaf(acc.z, nd, bb.z), 0.f);
    r.w = fmaxf(fmaf(acc.w, nd, bb.w), 0.f);
    ((float4*)H)[(size_t)n * 32 + li] = r;
  }
}

// ---------------- fused readout: one block per graph, no atomics ----------------
__global__ __launch_bounds__(256) void k_readout(
    const float* __restrict__ H, const float* __restrict__ Wv,
    const float* __restrict__ bv, const int* __restrict__ gstart,
    const float* __restrict__ Wc, const float* __restrict__ bc,
    float* __restrict__ out) {
  int g = blockIdx.x;
  int wid = threadIdx.x >> 6, lane = threadIdx.x & 63;
  int s0 = gstart[g], s1 = gstart[g + 1];
  float2 wv2 = ((const float2*)Wv)[lane];
  float bvs = bv[0];
  float ax = 0.f, ay = 0.f, dw = 0.f;
  for (int n = s0 + wid; n < s1; n += 4) {
    float2 h2 = ((const float2*)H)[(size_t)n * 64 + lane];
    float p = h2.x * wv2.x + h2.y * wv2.y;
#pragma unroll
    for (int off = 32; off > 0; off >>= 1) p += __shfl_xor(p, off);
    float w = 1.f / (1.f + expf(-(p + bvs)));
    ax += h2.x * w;
    ay += h2.y * w;
    dw += w;
  }
  __shared__ float2 snum[4][64];
  __shared__ float sden[4];
  __shared__ float hg[HID_C];
  snum[wid][lane] = make_float2(ax, ay);
  if (lane == 0) sden[wid] = dw;
  __syncthreads();
  if (wid == 0) {
    float2 a = snum[0][lane], b = snum[1][lane], c = snum[2][lane], d = snum[3][lane];
    float den = sden[0] + sden[1] + sden[2] + sden[3];
    float inv = (den > 0.f) ? 1.f / den : 0.f;
    hg[2 * lane] = (a.x + b.x + c.x + d.x) * inv;
    hg[2 * lane + 1] = (a.y + b.y + c.y + d.y) * inv;
  }
  __syncthreads();
  if (threadIdx.x < NCLS_C) {
    int c = threadIdx.x;
    float acc = 0.f;
    for (int k = 0; k < HID_C; ++k) acc = fmaf(hg[k], Wc[k * NCLS_C + c], acc);
    out[g * NCLS_C + c] = acc + bc[c];
  }
}

extern "C" void kernel_launch(void* const* d_in, const int* in_sizes, int n_in,
                              void* d_out, int out_size, void* d_ws, size_t ws_size,
                              hipStream_t stream) {
  const float* x = (const float*)d_in[0];
  const int* src = (const int*)d_in[1];
  const int* dst = (const int*)d_in[2];
  const int* gid = (const int*)d_in[3];
  const float* W[4] = {(const float*)d_in[4], (const float*)d_in[6],
                       (const float*)d_in[8], (const float*)d_in[10]};
  const float* b[4] = {(const float*)d_in[5], (const float*)d_in[7],
                       (const float*)d_in[9], (const float*)d_in[11]};
  const float* Wv = (const float*)d_in[12];
  const float* bv = (const float*)d_in[13];
  const float* Wc = (const float*)d_in[14];
  const float* bc = (const float*)d_in[15];
  float* out = (float*)d_out;

  char* ws = (char*)d_ws;
  size_t off = 0;
  auto alloc = [&](size_t bytes) -> char* {
    char* p = ws + off;
    off = (off + bytes + 255) & ~(size_t)255;
    return p;
  };
  int* cnt_out = (int*)alloc((size_t)N_NODES_C * 4);
  int* cnt_in = (int*)alloc((size_t)N_NODES_C * 4);
  int* gstart = (int*)alloc((size_t)(NGRAPH_C + 1) * 4);
  int* bcur = (int*)alloc((size_t)2 * NBKT * NREP * 4);
  int* ell = (int*)alloc((size_t)N_NODES_C * ELL_CAP * 4);
  int2* dstbkt = (int2*)alloc((size_t)NBKT * NREP * RCAP * 8);
  int* srcbkt = (int*)alloc((size_t)NBKT * NREP * RCAP * 4);
  float* bufU = (float*)alloc((size_t)N_NODES_C * HID_C * 4);
  float* bufH = (float*)alloc((size_t)N_NODES_C * HID_C * 4);
  (void)ws_size;
  (void)in_sizes;
  (void)n_in;
  (void)out_size;

  hipMemsetAsync(bcur, 0, (size_t)2 * NBKT * NREP * 4, stream);

  // B1 bucket-scatter || U1 = x @ W1 || gstart
  k_front<<<FRONT_BLOCKS, 256, 0, stream>>>(x, W[0], bufU, src, dst, bcur,
                                            dstbkt, srcbkt, gid, gstart);
  // ELL + cnt_in || cnt_out
  k_build<<<2 * NBKT, 256, 0, stream>>>(bcur, dstbkt, srcbkt, ell, cnt_in, cnt_out);

  int node_grid = (N_NODES_C + 3) / 4;
  k_agg<<<node_grid, 256, 0, stream>>>(bufU, cnt_in, cnt_out, ell, b[0], bufH);
  for (int l = 1; l < 4; ++l) {
    k_gemm<<<GEMM_BLOCKS, 256, 0, stream>>>(bufH, W[l], bufU);
    k_agg<<<node_grid, 256, 0, stream>>>(bufU, cnt_in, cnt_out, ell, b[l], bufH);
  }

  k_readout<<<NGRAPH_C, 256, 0, stream>>>(bufH, Wv, bv, gstart, Wc, bc, out);
}

// Round 12
// 817.945 us; speedup vs baseline: 1.1906x; 1.1906x over previous
//
#include <hip/hip_runtime.h>
#include <hip/hip_bf16.h>

#define N_NODES_C 100000
#define N_EDGES_C 1600000
#define HID_C 128
#define NCLS_C 16
#define NGRAPH_C 512
#define ELL_CAP 64
#define NXCD 8
#define XCD_RANGE ((N_NODES_C + NXCD - 1) / NXCD)  // 12500
#define PREP_GB 256
#define PREP_CHUNK (N_EDGES_C / PREP_GB)  // 6250

#define GEMM_BLOCKS ((N_NODES_C + 127) / 128)  // 782
#define PREP_BLOCKS 2048
#define GS_BLOCKS ((N_NODES_C + 255) / 256)  // 391
#define FRONT_BLOCKS (GEMM_BLOCKS + PREP_BLOCKS + GS_BLOCKS)

// ---------------- GEMM body (pure U = A @ W, no scale), shared ----------------
__device__ __forceinline__ void gemm_body(
    const float* __restrict__ A, const float* __restrict__ W,
    float* __restrict__ U, int m0, float (*sA)[132], float (*sB)[132]) {
  int t = threadIdx.x;
  int tx = t & 15, ty = t >> 4;

  float acc[8][8];
#pragma unroll
  for (int i = 0; i < 8; ++i)
#pragma unroll
    for (int j = 0; j < 8; ++j) acc[i][j] = 0.f;

  int a_c4 = (t & 7) * 4;
  int a_r = t >> 3;
  int w_n4 = (t & 31) * 4;
  int w_k = t >> 5;

  for (int k0 = 0; k0 < HID_C; k0 += 32) {
#pragma unroll
    for (int rr = 0; rr < 4; ++rr) {
      int r = rr * 32 + a_r;
      int row = m0 + r;
      float4 v = make_float4(0.f, 0.f, 0.f, 0.f);
      if (row < N_NODES_C) v = *(const float4*)&A[(size_t)row * HID_C + k0 + a_c4];
      sA[a_c4 + 0][r] = v.x;
      sA[a_c4 + 1][r] = v.y;
      sA[a_c4 + 2][r] = v.z;
      sA[a_c4 + 3][r] = v.w;
    }
#pragma unroll
    for (int i = 0; i < 4; ++i) {
      int kc = i * 8 + w_k;
      float4 v = *(const float4*)&W[(size_t)(k0 + kc) * HID_C + w_n4];
      *(float4*)&sB[kc][w_n4] = v;
    }
    __syncthreads();

#pragma unroll 4
    for (int kk = 0; kk < 32; ++kk) {
      float4 a0 = *(const float4*)&sA[kk][ty * 8];
      float4 a1 = *(const float4*)&sA[kk][ty * 8 + 4];
      float4 bb0 = *(const float4*)&sB[kk][tx * 8];
      float4 bb1 = *(const float4*)&sB[kk][tx * 8 + 4];
      float a[8] = {a0.x, a0.y, a0.z, a0.w, a1.x, a1.y, a1.z, a1.w};
      float b[8] = {bb0.x, bb0.y, bb0.z, bb0.w, bb1.x, bb1.y, bb1.z, bb1.w};
#pragma unroll
      for (int i = 0; i < 8; ++i)
#pragma unroll
        for (int j = 0; j < 8; ++j) acc[i][j] = fmaf(a[i], b[j], acc[i][j]);
    }
    __syncthreads();
  }

#pragma unroll
  for (int i = 0; i < 8; ++i) {
    int row = m0 + ty * 8 + i;
    if (row < N_NODES_C) {
      float4 v0 = {acc[i][0], acc[i][1], acc[i][2], acc[i][3]};
      float4 v1 = {acc[i][4], acc[i][5], acc[i][6], acc[i][7]};
      float4* p = (float4*)&U[(size_t)row * HID_C + tx * 8];
      p[0] = v0;
      p[1] = v1;
    }
  }
}

// ---------------- FRONT: gemm1 || XCD-local prep || gstart ----------------
// Prep blocks read their PHYSICAL die id (HW_REG_XCC_ID) and claim edge-chunks
// from their die's work counter, handling ONLY the node range owned by that
// die. All cnt/ELL lines for a range are then touched by exactly one XCD's L2
// -> lines stay resident until fully filled -> near-dense writeback.
__global__ __launch_bounds__(256) void k_front(
    const float* __restrict__ x, const float* __restrict__ W1,
    float* __restrict__ U1, const int* __restrict__ src,
    const int* __restrict__ dst, int* cnt_out, int* cursor,
    int* __restrict__ ell, int* xcd_cnt, const int* __restrict__ gid,
    int* __restrict__ gstart) {
  __shared__ float sA[32][132];
  __shared__ float sB[32][132];
  __shared__ int s_chunk;
  int bid = blockIdx.x;
  if (bid < GEMM_BLOCKS) {
    gemm_body(x, W1, U1, bid * 128, sA, sB);
  } else if (bid < GEMM_BLOCKS + PREP_BLOCKS) {
    unsigned int xcd;
    asm volatile("s_getreg_b32 %0, hwreg(HW_REG_XCC_ID)" : "=s"(xcd));
    xcd &= (NXCD - 1);
    int lo = (int)xcd * XCD_RANGE;
    for (;;) {
      if (threadIdx.x == 0) s_chunk = atomicAdd(&xcd_cnt[xcd], 1);
      __syncthreads();
      int chunk = s_chunk;
      __syncthreads();
      if (chunk >= PREP_GB) break;
      int e0 = chunk * PREP_CHUNK;
      int e1 = e0 + PREP_CHUNK;
      for (int i = e0 + threadIdx.x; i < e1; i += 256) {
        int s = src[i];
        int d = dst[i];
        if ((unsigned)(s - lo) < (unsigned)XCD_RANGE) atomicAdd(&cnt_out[s], 1);
        if ((unsigned)(d - lo) < (unsigned)XCD_RANGE) {
          int p = atomicAdd(&cursor[d], 1);
          if (p < ELL_CAP) ell[((size_t)d << 6) + p] = s;
        }
      }
    }
  } else {
    int n = (bid - GEMM_BLOCKS - PREP_BLOCKS) * 256 + threadIdx.x;
    if (n >= N_NODES_C) return;
    int g = gid[n];
    int gp = (n == 0) ? -1 : gid[n - 1];
    for (int k = gp + 1; k <= g; ++k) gstart[k] = n;
    if (n == N_NODES_C - 1) {
      for (int k = g + 1; k <= NGRAPH_C; ++k) gstart[k] = N_NODES_C;
    }
  }
}

// ---------------- plain GEMM kernel (layers 2..4): U = H @ W ----------------
__global__ __launch_bounds__(256) void k_gemm(
    const float* __restrict__ A, const float* __restrict__ W,
    float* __restrict__ U) {
  __shared__ float sA[32][132];
  __shared__ float sB[32][132];
  gemm_body(A, W, U, blockIdx.x * 128, sA, sB);
}

// ---------------- aggregation (ELL, deferred norms) ----------------
// H[n] = relu( nd[n] * sum_e ns[ell[n][e]] * U[ell[n][e]] + b )
__global__ __launch_bounds__(256) void k_agg(
    const float* __restrict__ U, const int* __restrict__ cnt_in,
    const int* __restrict__ cnt_out, const int* __restrict__ ell,
    const float* __restrict__ bias, float* __restrict__ H) {
  int wid = threadIdx.x >> 6, lane = threadIdx.x & 63;
  int half = lane >> 5, li = lane & 31;
  int n = blockIdx.x * 4 + wid;
  if (n >= N_NODES_C) return;
  const int* lst = ell + ((size_t)n << 6);
  int degfull = cnt_in[n];
  int deg = degfull > ELL_CAP ? ELL_CAP : degfull;
  const float4* U4 = (const float4*)U;
  float4 acc = make_float4(0.f, 0.f, 0.f, 0.f);
  int e = 0;
  for (; e + 8 <= deg; e += 8) {
    int i0 = lst[e + 0 + half], i1 = lst[e + 2 + half];
    int i2 = lst[e + 4 + half], i3 = lst[e + 6 + half];
    float s0 = 1.f / sqrtf((float)cnt_out[i0]);
    float s1 = 1.f / sqrtf((float)cnt_out[i1]);
    float s2 = 1.f / sqrtf((float)cnt_out[i2]);
    float s3 = 1.f / sqrtf((float)cnt_out[i3]);
    float4 v0 = U4[(size_t)i0 * 32 + li];
    float4 v1 = U4[(size_t)i1 * 32 + li];
    float4 v2 = U4[(size_t)i2 * 32 + li];
    float4 v3 = U4[(size_t)i3 * 32 + li];
    acc.x = fmaf(v0.x, s0, fmaf(v1.x, s1, fmaf(v2.x, s2, fmaf(v3.x, s3, acc.x))));
    acc.y = fmaf(v0.y, s0, fmaf(v1.y, s1, fmaf(v2.y, s2, fmaf(v3.y, s3, acc.y))));
    acc.z = fmaf(v0.z, s0, fmaf(v1.z, s1, fmaf(v2.z, s2, fmaf(v3.z, s3, acc.z))));
    acc.w = fmaf(v0.w, s0, fmaf(v1.w, s1, fmaf(v2.w, s2, fmaf(v3.w, s3, acc.w))));
  }
  for (; e + 2 <= deg; e += 2) {
    int i = lst[e + half];
    float s = 1.f / sqrtf((float)cnt_out[i]);
    float4 v = U4[(size_t)i * 32 + li];
    acc.x = fmaf(v.x, s, acc.x);
    acc.y = fmaf(v.y, s, acc.y);
    acc.z = fmaf(v.z, s, acc.z);
    acc.w = fmaf(v.w, s, acc.w);
  }
  if (e < deg) {  // odd tail: low half only
    int i = lst[e];
    float s = 1.f / sqrtf((float)cnt_out[i]);
    float4 v = U4[(size_t)i * 32 + li];
    if (half == 0) {
      acc.x = fmaf(v.x, s, acc.x);
      acc.y = fmaf(v.y, s, acc.y);
      acc.z = fmaf(v.z, s, acc.z);
      acc.w = fmaf(v.w, s, acc.w);
    }
  }
  acc.x += __shfl_xor(acc.x, 32);
  acc.y += __shfl_xor(acc.y, 32);
  acc.z += __shfl_xor(acc.z, 32);
  acc.w += __shfl_xor(acc.w, 32);
  if (half == 0) {
    float nd = 1.f / sqrtf(fmaxf((float)degfull, 1.f));
    float4 bb = ((const float4*)bias)[li];
    float4 r;
    r.x = fmaxf(fmaf(acc.x, nd, bb.x), 0.f);
    r.y = fmaxf(fmaf(acc.y, nd, bb.y), 0.f);
    r.z = fmaxf(fmaf(acc.z, nd, bb.z), 0.f);
    r.w = fmaxf(fmaf(acc.w, nd, bb.w), 0.f);
    ((float4*)H)[(size_t)n * 32 + li] = r;
  }
}

// ---------------- fused readout: one block per graph, no atomics ----------------
__global__ __launch_bounds__(256) void k_readout(
    const float* __restrict__ H, const float* __restrict__ Wv,
    const float* __restrict__ bv, const int* __restrict__ gstart,
    const float* __restrict__ Wc, const float* __restrict__ bc,
    float* __restrict__ out) {
  int g = blockIdx.x;
  int wid = threadIdx.x >> 6, lane = threadIdx.x & 63;
  int s0 = gstart[g], s1 = gstart[g + 1];
  float2 wv2 = ((const float2*)Wv)[lane];
  float bvs = bv[0];
  float ax = 0.f, ay = 0.f, dw = 0.f;
  for (int n = s0 + wid; n < s1; n += 4) {
    float2 h2 = ((const float2*)H)[(size_t)n * 64 + lane];
    float p = h2.x * wv2.x + h2.y * wv2.y;
#pragma unroll
    for (int off = 32; off > 0; off >>= 1) p += __shfl_xor(p, off);
    float w = 1.f / (1.f + expf(-(p + bvs)));
    ax += h2.x * w;
    ay += h2.y * w;
    dw += w;
  }
  __shared__ float2 snum[4][64];
  __shared__ float sden[4];
  __shared__ float hg[HID_C];
  snum[wid][lane] = make_float2(ax, ay);
  if (lane == 0) sden[wid] = dw;
  __syncthreads();
  if (wid == 0) {
    float2 a = snum[0][lane], b = snum[1][lane], c = snum[2][lane], d = snum[3][lane];
    float den = sden[0] + sden[1] + sden[2] + sden[3];
    float inv = (den > 0.f) ? 1.f / den : 0.f;
    hg[2 * lane] = (a.x + b.x + c.x + d.x) * inv;
    hg[2 * lane + 1] = (a.y + b.y + c.y + d.y) * inv;
  }
  __syncthreads();
  if (threadIdx.x < NCLS_C) {
    int c = threadIdx.x;
    float acc = 0.f;
    for (int k = 0; k < HID_C; ++k) acc = fmaf(hg[k], Wc[k * NCLS_C + c], acc);
    out[g * NCLS_C + c] = acc + bc[c];
  }
}

extern "C" void kernel_launch(void* const* d_in, const int* in_sizes, int n_in,
                              void* d_out, int out_size, void* d_ws, size_t ws_size,
                              hipStream_t stream) {
  const float* x = (const float*)d_in[0];
  const int* src = (const int*)d_in[1];
  const int* dst = (const int*)d_in[2];
  const int* gid = (const int*)d_in[3];
  const float* W[4] = {(const float*)d_in[4], (const float*)d_in[6],
                       (const float*)d_in[8], (const float*)d_in[10]};
  const float* b[4] = {(const float*)d_in[5], (const float*)d_in[7],
                       (const float*)d_in[9], (const float*)d_in[11]};
  const float* Wv = (const float*)d_in[12];
  const float* bv = (const float*)d_in[13];
  const float* Wc = (const float*)d_in[14];
  const float* bc = (const float*)d_in[15];
  float* out = (float*)d_out;

  char* ws = (char*)d_ws;
  size_t off = 0;
  auto alloc = [&](size_t bytes) -> char* {
    char* p = ws + off;
    off = (off + bytes + 255) & ~(size_t)255;
    return p;
  };
  int* cnt_out = (int*)alloc((size_t)N_NODES_C * 4);
  int* cursor = (int*)alloc((size_t)N_NODES_C * 4);  // = cnt_in after k_front
  int* gstart = (int*)alloc((size_t)(NGRAPH_C + 1) * 4);
  int* xcd_cnt = (int*)alloc((size_t)NXCD * 4);
  int* ell = (int*)alloc((size_t)N_NODES_C * ELL_CAP * 4);
  float* bufU = (float*)alloc((size_t)N_NODES_C * HID_C * 4);
  float* bufH = (float*)alloc((size_t)N_NODES_C * HID_C * 4);
  (void)ws_size;
  (void)in_sizes;
  (void)n_in;
  (void)out_size;

  hipMemsetAsync(cnt_out, 0, (size_t)N_NODES_C * 4, stream);
  hipMemsetAsync(cursor, 0, (size_t)N_NODES_C * 4, stream);
  hipMemsetAsync(xcd_cnt, 0, (size_t)NXCD * 4, stream);

  // U1 = x @ W1  ||  XCD-local prep (cnt_out, cnt_in, ELL)  ||  gstart
  k_front<<<FRONT_BLOCKS, 256, 0, stream>>>(x, W[0], bufU, src, dst, cnt_out,
                                            cursor, ell, xcd_cnt, gid, gstart);

  int node_grid = (N_NODES_C + 3) / 4;
  k_agg<<<node_grid, 256, 0, stream>>>(bufU, cursor, cnt_out, ell, b[0], bufH);
  for (int l = 1; l < 4; ++l) {
    k_gemm<<<GEMM_BLOCKS, 256, 0, stream>>>(bufH, W[l], bufU);
    k_agg<<<node_grid, 256, 0, stream>>>(bufU, cursor, cnt_out, ell, b[l], bufH);
  }

  k_readout<<<NGRAPH_C, 256, 0, stream>>>(bufH, Wv, bv, gstart, Wc, bc, out);
}

// Round 13
// 801.194 us; speedup vs baseline: 1.2155x; 1.0209x over previous
//
#include <hip/hip_runtime.h>
#include <hip/hip_bf16.h>

#define N_NODES_C 100000
#define N_EDGES_C 1600000
#define HID_C 128
#define NCLS_C 16
#define NGRAPH_C 512
#define ELL_CAP 64
#define PREP_GROUPS 8
#define PREP_RANGE ((N_NODES_C + PREP_GROUPS - 1) / PREP_GROUPS)  // 12500
#define PREP_GB 256
#define PREP_CHUNK (N_EDGES_C / PREP_GB)  // 6250

#define GEMM_BLOCKS ((N_NODES_C + 127) / 128)  // 782
#define PREP_BLOCKS (PREP_GROUPS * PREP_GB)    // 2048
#define GS_BLOCKS ((N_NODES_C + 255) / 256)    // 391
#define FRONT_BLOCKS (GEMM_BLOCKS + PREP_BLOCKS + GS_BLOCKS)

// ---------------- GEMM body; optional ns-scale epilogue (scale==nullptr -> raw) ----
__device__ __forceinline__ void gemm_body(
    const float* __restrict__ A, const float* __restrict__ W,
    float* __restrict__ U, int m0, const int* __restrict__ cnt_out,
    float (*sA)[132], float (*sB)[132]) {
  int t = threadIdx.x;
  int tx = t & 15, ty = t >> 4;

  float acc[8][8];
#pragma unroll
  for (int i = 0; i < 8; ++i)
#pragma unroll
    for (int j = 0; j < 8; ++j) acc[i][j] = 0.f;

  int a_c4 = (t & 7) * 4;
  int a_r = t >> 3;
  int w_n4 = (t & 31) * 4;
  int w_k = t >> 5;

  for (int k0 = 0; k0 < HID_C; k0 += 32) {
#pragma unroll
    for (int rr = 0; rr < 4; ++rr) {
      int r = rr * 32 + a_r;
      int row = m0 + r;
      float4 v = make_float4(0.f, 0.f, 0.f, 0.f);
      if (row < N_NODES_C) v = *(const float4*)&A[(size_t)row * HID_C + k0 + a_c4];
      sA[a_c4 + 0][r] = v.x;
      sA[a_c4 + 1][r] = v.y;
      sA[a_c4 + 2][r] = v.z;
      sA[a_c4 + 3][r] = v.w;
    }
#pragma unroll
    for (int i = 0; i < 4; ++i) {
      int kc = i * 8 + w_k;
      float4 v = *(const float4*)&W[(size_t)(k0 + kc) * HID_C + w_n4];
      *(float4*)&sB[kc][w_n4] = v;
    }
    __syncthreads();

#pragma unroll 4
    for (int kk = 0; kk < 32; ++kk) {
      float4 a0 = *(const float4*)&sA[kk][ty * 8];
      float4 a1 = *(const float4*)&sA[kk][ty * 8 + 4];
      float4 bb0 = *(const float4*)&sB[kk][tx * 8];
      float4 bb1 = *(const float4*)&sB[kk][tx * 8 + 4];
      float a[8] = {a0.x, a0.y, a0.z, a0.w, a1.x, a1.y, a1.z, a1.w};
      float b[8] = {bb0.x, bb0.y, bb0.z, bb0.w, bb1.x, bb1.y, bb1.z, bb1.w};
#pragma unroll
      for (int i = 0; i < 8; ++i)
#pragma unroll
        for (int j = 0; j < 8; ++j) acc[i][j] = fmaf(a[i], b[j], acc[i][j]);
    }
    __syncthreads();
  }

#pragma unroll
  for (int i = 0; i < 8; ++i) {
    int row = m0 + ty * 8 + i;
    if (row < N_NODES_C) {
      float sc = cnt_out ? (1.f / sqrtf(fmaxf((float)cnt_out[row], 1.f))) : 1.f;
      float4 v0 = {acc[i][0] * sc, acc[i][1] * sc, acc[i][2] * sc, acc[i][3] * sc};
      float4 v1 = {acc[i][4] * sc, acc[i][5] * sc, acc[i][6] * sc, acc[i][7] * sc};
      float4* p = (float4*)&U[(size_t)row * HID_C + tx * 8];
      p[0] = v0;
      p[1] = v1;
    }
  }
}

// ---------------- FRONT: gemm1 (raw U1 = x@W1) || prep || gstart ----------------
__global__ __launch_bounds__(256) void k_front(
    const float* __restrict__ x, const float* __restrict__ W1,
    float* __restrict__ U1, const int* __restrict__ src,
    const int* __restrict__ dst, int* cnt_out, int* cursor,
    int* __restrict__ ell, const int* __restrict__ gid,
    int* __restrict__ gstart) {
  __shared__ float sA[32][132];
  __shared__ float sB[32][132];
  int bid = blockIdx.x;
  if (bid < GEMM_BLOCKS) {
    gemm_body(x, W1, U1, bid * 128, nullptr, sA, sB);
  } else if (bid < GEMM_BLOCKS + PREP_BLOCKS) {
    int grp = bid & (PREP_GROUPS - 1);
    int gb = (bid - GEMM_BLOCKS) >> 3;
    int lo = grp * PREP_RANGE;
    int e0 = gb * PREP_CHUNK;
    int e1 = e0 + PREP_CHUNK;
    for (int i = e0 + threadIdx.x; i < e1; i += 256) {
      int s = src[i];
      int d = dst[i];
      if ((unsigned)(s - lo) < (unsigned)PREP_RANGE) atomicAdd(&cnt_out[s], 1);
      if ((unsigned)(d - lo) < (unsigned)PREP_RANGE) {
        int p = atomicAdd(&cursor[d], 1);
        if (p < ELL_CAP) ell[((size_t)d << 6) + p] = s;
      }
    }
  } else {
    int n = (bid - GEMM_BLOCKS - PREP_BLOCKS) * 256 + threadIdx.x;
    if (n >= N_NODES_C) return;
    int g = gid[n];
    int gp = (n == 0) ? -1 : gid[n - 1];
    for (int k = gp + 1; k <= g; ++k) gstart[k] = n;
    if (n == N_NODES_C - 1) {
      for (int k = g + 1; k <= NGRAPH_C; ++k) gstart[k] = N_NODES_C;
    }
  }
}

// ---------------- GEMM with ns epilogue (layers 2..4): U = (H @ W) * ns ----------------
__global__ __launch_bounds__(256) void k_gemm_rowscale(
    const float* __restrict__ A, const float* __restrict__ W,
    const int* __restrict__ cnt_out, float* __restrict__ U) {
  __shared__ float sA[32][132];
  __shared__ float sB[32][132];
  gemm_body(A, W, U, blockIdx.x * 128, cnt_out, sA, sB);
}

// ---------------- aggregation: pre-scaled U (layers 2..4) ----------------
// H[n] = relu( nd[n] * sum_e U[ell[n][e]] + b ); U already carries ns.
// Low half-wave: edges e..e+3 (one int4 idx load); high: e+4..e+7.
__global__ __launch_bounds__(256) void k_agg(
    const float* __restrict__ U, const int* __restrict__ cnt_in,
    const int* __restrict__ ell, const float* __restrict__ bias,
    float* __restrict__ H) {
  int wid = threadIdx.x >> 6, lane = threadIdx.x & 63;
  int half = lane >> 5, li = lane & 31;
  int n = blockIdx.x * 4 + wid;
  if (n >= N_NODES_C) return;
  const int* lst = ell + ((size_t)n << 6);
  int degfull = cnt_in[n];
  int deg = degfull > ELL_CAP ? ELL_CAP : degfull;
  const float4* U4 = (const float4*)U;
  float4 acc = make_float4(0.f, 0.f, 0.f, 0.f);
  int e = 0;
  for (; e + 8 <= deg; e += 8) {
    int4 ii = *(const int4*)&lst[e + 4 * half];
    float4 v0 = U4[(size_t)ii.x * 32 + li];
    float4 v1 = U4[(size_t)ii.y * 32 + li];
    float4 v2 = U4[(size_t)ii.z * 32 + li];
    float4 v3 = U4[(size_t)ii.w * 32 + li];
    acc.x += v0.x + v1.x + v2.x + v3.x;
    acc.y += v0.y + v1.y + v2.y + v3.y;
    acc.z += v0.z + v1.z + v2.z + v3.z;
    acc.w += v0.w + v1.w + v2.w + v3.w;
  }
  for (; e + 2 <= deg; e += 2) {
    int i = lst[e + half];
    float4 v = U4[(size_t)i * 32 + li];
    acc.x += v.x;
    acc.y += v.y;
    acc.z += v.z;
    acc.w += v.w;
  }
  if (e < deg) {
    int i = lst[e];
    float4 v = U4[(size_t)i * 32 + li];
    if (half == 0) {
      acc.x += v.x;
      acc.y += v.y;
      acc.z += v.z;
      acc.w += v.w;
    }
  }
  acc.x += __shfl_xor(acc.x, 32);
  acc.y += __shfl_xor(acc.y, 32);
  acc.z += __shfl_xor(acc.z, 32);
  acc.w += __shfl_xor(acc.w, 32);
  if (half == 0) {
    float nd = 1.f / sqrtf(fmaxf((float)degfull, 1.f));
    float4 bb = ((const float4*)bias)[li];
    float4 r;
    r.x = fmaxf(fmaf(acc.x, nd, bb.x), 0.f);
    r.y = fmaxf(fmaf(acc.y, nd, bb.y), 0.f);
    r.z = fmaxf(fmaf(acc.z, nd, bb.z), 0.f);
    r.w = fmaxf(fmaf(acc.w, nd, bb.w), 0.f);
    ((float4*)H)[(size_t)n * 32 + li] = r;
  }
}

// ---------------- aggregation, deferred ns (layer 1; U1 is raw x@W1) ----------------
__global__ __launch_bounds__(256) void k_agg_defer(
    const float* __restrict__ U, const int* __restrict__ cnt_in,
    const int* __restrict__ cnt_out, const int* __restrict__ ell,
    const float* __restrict__ bias, float* __restrict__ H) {
  int wid = threadIdx.x >> 6, lane = threadIdx.x & 63;
  int half = lane >> 5, li = lane & 31;
  int n = blockIdx.x * 4 + wid;
  if (n >= N_NODES_C) return;
  const int* lst = ell + ((size_t)n << 6);
  int degfull = cnt_in[n];
  int deg = degfull > ELL_CAP ? ELL_CAP : degfull;
  const float4* U4 = (const float4*)U;
  float4 acc = make_float4(0.f, 0.f, 0.f, 0.f);
  int e = 0;
  for (; e + 8 <= deg; e += 8) {
    int4 ii = *(const int4*)&lst[e + 4 * half];
    float s0 = 1.f / sqrtf((float)cnt_out[ii.x]);
    float s1 = 1.f / sqrtf((float)cnt_out[ii.y]);
    float s2 = 1.f / sqrtf((float)cnt_out[ii.z]);
    float s3 = 1.f / sqrtf((float)cnt_out[ii.w]);
    float4 v0 = U4[(size_t)ii.x * 32 + li];
    float4 v1 = U4[(size_t)ii.y * 32 + li];
    float4 v2 = U4[(size_t)ii.z * 32 + li];
    float4 v3 = U4[(size_t)ii.w * 32 + li];
    acc.x = fmaf(v0.x, s0, fmaf(v1.x, s1, fmaf(v2.x, s2, fmaf(v3.x, s3, acc.x))));
    acc.y = fmaf(v0.y, s0, fmaf(v1.y, s1, fmaf(v2.y, s2, fmaf(v3.y, s3, acc.y))));
    acc.z = fmaf(v0.z, s0, fmaf(v1.z, s1, fmaf(v2.z, s2, fmaf(v3.z, s3, acc.z))));
    acc.w = fmaf(v0.w, s0, fmaf(v1.w, s1, fmaf(v2.w, s2, fmaf(v3.w, s3, acc.w))));
  }
  for (; e + 2 <= deg; e += 2) {
    int i = lst[e + half];
    float s = 1.f / sqrtf((float)cnt_out[i]);
    float4 v = U4[(size_t)i * 32 + li];
    acc.x = fmaf(v.x, s, acc.x);
    acc.y = fmaf(v.y, s, acc.y);
    acc.z = fmaf(v.z, s, acc.z);
    acc.w = fmaf(v.w, s, acc.w);
  }
  if (e < deg) {
    int i = lst[e];
    float s = 1.f / sqrtf((float)cnt_out[i]);
    float4 v = U4[(size_t)i * 32 + li];
    if (half == 0) {
      acc.x = fmaf(v.x, s, acc.x);
      acc.y = fmaf(v.y, s, acc.y);
      acc.z = fmaf(v.z, s, acc.z);
      acc.w = fmaf(v.w, s, acc.w);
    }
  }
  acc.x += __shfl_xor(acc.x, 32);
  acc.y += __shfl_xor(acc.y, 32);
  acc.z += __shfl_xor(acc.z, 32);
  acc.w += __shfl_xor(acc.w, 32);
  if (half == 0) {
    float nd = 1.f / sqrtf(fmaxf((float)degfull, 1.f));
    float4 bb = ((const float4*)bias)[li];
    float4 r;
    r.x = fmaxf(fmaf(acc.x, nd, bb.x), 0.f);
    r.y = fmaxf(fmaf(acc.y, nd, bb.y), 0.f);
    r.z = fmaxf(fmaf(acc.z, nd, bb.z), 0.f);
    r.w = fmaxf(fmaf(acc.w, nd, bb.w), 0.f);
    ((float4*)H)[(size_t)n * 32 + li] = r;
  }
}

// ---------------- fused readout: one block per graph, no atomics ----------------
__global__ __launch_bounds__(256) void k_readout(
    const float* __restrict__ H, const float* __restrict__ Wv,
    const float* __restrict__ bv, const int* __restrict__ gstart,
    const float* __restrict__ Wc, const float* __restrict__ bc,
    float* __restrict__ out) {
  int g = blockIdx.x;
  int wid = threadIdx.x >> 6, lane = threadIdx.x & 63;
  int s0 = gstart[g], s1 = gstart[g + 1];
  float2 wv2 = ((const float2*)Wv)[lane];
  float bvs = bv[0];
  float ax = 0.f, ay = 0.f, dw = 0.f;
  for (int n = s0 + wid; n < s1; n += 4) {
    float2 h2 = ((const float2*)H)[(size_t)n * 64 + lane];
    float p = h2.x * wv2.x + h2.y * wv2.y;
#pragma unroll
    for (int off = 32; off > 0; off >>= 1) p += __shfl_xor(p, off);
    float w = 1.f / (1.f + expf(-(p + bvs)));
    ax += h2.x * w;
    ay += h2.y * w;
    dw += w;
  }
  __shared__ float2 snum[4][64];
  __shared__ float sden[4];
  __shared__ float hg[HID_C];
  snum[wid][lane] = make_float2(ax, ay);
  if (lane == 0) sden[wid] = dw;
  __syncthreads();
  if (wid == 0) {
    float2 a = snum[0][lane], b = snum[1][lane], c = snum[2][lane], d = snum[3][lane];
    float den = sden[0] + sden[1] + sden[2] + sden[3];
    float inv = (den > 0.f) ? 1.f / den : 0.f;
    hg[2 * lane] = (a.x + b.x + c.x + d.x) * inv;
    hg[2 * lane + 1] = (a.y + b.y + c.y + d.y) * inv;
  }
  __syncthreads();
  if (threadIdx.x < NCLS_C) {
    int c = threadIdx.x;
    float acc = 0.f;
    for (int k = 0; k < HID_C; ++k) acc = fmaf(hg[k], Wc[k * NCLS_C + c], acc);
    out[g * NCLS_C + c] = acc + bc[c];
  }
}

extern "C" void kernel_launch(void* const* d_in, const int* in_sizes, int n_in,
                              void* d_out, int out_size, void* d_ws, size_t ws_size,
                              hipStream_t stream) {
  const float* x = (const float*)d_in[0];
  const int* src = (const int*)d_in[1];
  const int* dst = (const int*)d_in[2];
  const int* gid = (const int*)d_in[3];
  const float* W[4] = {(const float*)d_in[4], (const float*)d_in[6],
                       (const float*)d_in[8], (const float*)d_in[10]};
  const float* b[4] = {(const float*)d_in[5], (const float*)d_in[7],
                       (const float*)d_in[9], (const float*)d_in[11]};
  const float* Wv = (const float*)d_in[12];
  const float* bv = (const float*)d_in[13];
  const float* Wc = (const float*)d_in[14];
  const float* bc = (const float*)d_in[15];
  float* out = (float*)d_out;

  char* ws = (char*)d_ws;
  size_t off = 0;
  auto alloc = [&](size_t bytes) -> char* {
    char* p = ws + off;
    off = (off + bytes + 255) & ~(size_t)255;
    return p;
  };
  int* cnt_out = (int*)alloc((size_t)N_NODES_C * 4);
  int* cursor = (int*)alloc((size_t)N_NODES_C * 4);  // = cnt_in after k_front
  int* gstart = (int*)alloc((size_t)(NGRAPH_C + 1) * 4);
  int* ell = (int*)alloc((size_t)N_NODES_C * ELL_CAP * 4);
  float* bufU = (float*)alloc((size_t)N_NODES_C * HID_C * 4);
  float* bufH = (float*)alloc((size_t)N_NODES_C * HID_C * 4);
  (void)ws_size;
  (void)in_sizes;
  (void)n_in;
  (void)out_size;

  hipMemsetAsync(cnt_out, 0, (size_t)N_NODES_C * 4, stream);
  hipMemsetAsync(cursor, 0, (size_t)N_NODES_C * 4, stream);

  // U1 = x @ W1 (raw)  ||  prep  ||  gstart
  k_front<<<FRONT_BLOCKS, 256, 0, stream>>>(x, W[0], bufU, src, dst, cnt_out,
                                            cursor, ell, gid, gstart);

  int node_grid = (N_NODES_C + 3) / 4;
  // H1 = relu(nd * sum ns*U1 + b1)  (deferred ns)
  k_agg_defer<<<node_grid, 256, 0, stream>>>(bufU, cursor, cnt_out, ell, b[0], bufH);
  for (int l = 1; l < 4; ++l) {
    // U = (H @ W) * ns
    k_gemm_rowscale<<<GEMM_BLOCKS, 256, 0, stream>>>(bufH, W[l], cnt_out, bufU);
    // H = relu(nd * sum U + b)
    k_agg<<<node_grid, 256, 0, stream>>>(bufU, cursor, ell, b[l], bufH);
  }

  k_readout<<<NGRAPH_C, 256, 0, stream>>>(bufH, Wv, bv, gstart, Wc, bc, out);
}